// Round 1
// baseline (454.904 us; speedup 1.0000x reference)
//
#include <hip/hip_runtime.h>
#include <math.h>

// CTreeC loss: DEPTH=7, V=255 states, B=64, T=50, vocab=5000.
// R4: FUSED, ZERO-WORKSPACE kernel. rocprof showed the 439 us measurement is
// dominated by two ~200 us __amd_rocclr_fillBufferAligned dispatches per timed
// iteration, each writing 1.3056 GB (= 4x log_probs) at 81% HBM peak -- the
// harness re-poisoning the workspace. Our actual kernels were only ~40 us.
// This version never touches d_ws: gather runs with 8 waves into LDS
// (e_lds[t][v] = exp(extracted), 50 KB), then wave 0 runs the verified
// linear-domain telescoped scan (identical FP ops to R3's scan_kernel,
// absmax 0.0 there).
//
// Linear-domain scan recap: the reference's per-step logC normalization
// telescopes -- dividing curr by S = sum_OUT(curr) while adding log(S) to acc
// is exact, computable in linear space. Per step: 4 muls + 6-round wave
// sum-reduce + __logf + rcp.
//
// Tree structure (in-order numbering), p = v+1:
//   START <=> p power of 2; END <=> p + (p&-p) == 256; OUT = non-END (247).
//   non-START x: s=ctz(p), j=x-2^s, k=ctz(p&(p-1)); sources {j-2^a: a<k}.

#define TT 50
#define BB 64
#define VOCAB 5000
#define NS 255
#define NSP 256
#define LOG_EPS_F (-64.0f)
#define EPS_F 1.6038109389511818e-28f  // exp(-64)

__device__ __forceinline__ float wred_sum(float x) {
#pragma unroll
    for (int m = 32; m >= 1; m >>= 1) x += __shfl_xor(x, m);
    return x;
}

// One block per batch element b. 512 threads (8 waves):
//   phase 1 (all waves): gather exp(log_probs[v][b][tgt[t]]) -> e_lds[t][v]
//   phase 2 (wave 0):    serial linear-domain scan over t
__global__ __launch_bounds__(512) void ctreec_fused_lin(
    const float* __restrict__ log_probs,
    const int* __restrict__ targets,
    const int* __restrict__ target_lengths,
    float* __restrict__ out)
{
    const int b = blockIdx.x;
    const int tid = threadIdx.x;

    __shared__ float e_lds[TT * NSP];   // 50 KB: [t][v], v=255 padded with 0
    __shared__ float outv[NSP];
    __shared__ int tgts[TT];

    const int len = target_lengths[b];

    if (tid < TT) tgts[tid] = targets[tid * BB + b];
    __syncthreads();

    // ---- phase 1: gather ----
    // v fixed per thread, t strided by 2: all of a thread's loads hit the same
    // 20 KB (v,b)-row of log_probs (good L2 locality); independent loads
    // pipeline up to vmcnt depth. LDS writes are stride-1 across each wave.
    {
        const int v = tid & (NSP - 1);
        const int th = tid >> 8;                 // 0 or 1
        if (v < NS) {
            const float* row =
                log_probs + (size_t)v * (BB * VOCAB) + (size_t)b * VOCAB;
            for (int t = th; t < len; t += 2)
                e_lds[t * NSP + v] = __expf(row[tgts[t]]);
        } else {
            // pad slot: must be finite (prev=0 * garbage-NaN would poison sums)
            for (int t = th; t < len; t += 2)
                e_lds[t * NSP + v] = 0.0f;
        }
    }
    __syncthreads();

    if (tid >= 64) return;   // waves 1..7 done; wave 0 scans alone.
    // From here: single wave. Same-wave LDS ops execute in order (DS pipe is
    // in-order per wave), so no s_barrier is needed; wave_barrier() below only
    // pins compiler scheduling across the cross-lane LDS handoff.

    const int lane = tid;
    const int vbase = lane * 4;

    // static tree structure for this lane's 4 nodes
    bool isend[4], isout[4];
    int kk[4], jj[4];
    float prev[4];
#pragma unroll
    for (int i = 0; i < 4; ++i) {
        int v = vbase + i;
        int p = v + 1;
        bool valid = (v < NS);
        bool pw2 = (p & (p - 1)) == 0;
        bool e_ = valid && ((p + (p & (-p))) == 256);
        isend[i] = e_;
        isout[i] = valid && !e_;
        prev[i] = (valid && pw2) ? 1.0f : 0.0f;
        if (valid && !pw2) {
            int s = __ffs(p) - 1;
            int q = p & (p - 1);
            kk[i] = __ffs(q) - 1;
            jj[i] = v - (1 << s);
        } else { kk[i] = 0; jj[i] = 0; }
    }

    const float4* ev = (const float4*)e_lds;
    float acc = 0.0f;
    float4 eA = ev[lane];                       // prefetch depth 1 (LDS)
    for (int t = 0; t < len; ++t) {
        float4 cur = eA;
        if (t + 1 < len) eA = ev[(t + 1) * 64 + lane];

        float c[4];
        c[0] = prev[0] * cur.x;
        c[1] = prev[1] * cur.y;
        c[2] = prev[2] * cur.z;
        c[3] = prev[3] * cur.w;

        if (t == len - 1) {
            float s = 0.0f;
#pragma unroll
            for (int i = 0; i < 4; ++i)
                if (isend[i]) s += c[i];
            s = wred_sum(s);
            acc += __logf(s);
        } else {
            // stage unnormalized curr in LDS; overlaps with the reduction
            *(float4*)&outv[vbase] = make_float4(c[0], c[1], c[2], c[3]);
            float s = 0.0f;
#pragma unroll
            for (int i = 0; i < 4; ++i)
                if (isout[i]) s += c[i];
            s = wred_sum(s);
            acc += __logf(s);
            float rinv = 1.0f / s;   // scaling error telescopes out exactly
            __builtin_amdgcn_wave_barrier();
            // new_prev[x] = rinv * sum over its <=7 sources
#pragma unroll
            for (int i = 0; i < 4; ++i) {
                float np_ = 0.0f;
                int bj = jj[i];
                int n = kk[i];
                for (int a = 0; a < n; ++a) np_ += outv[bj - (1 << a)];
                prev[i] = np_ * rinv;
            }
            __builtin_amdgcn_wave_barrier();
        }
    }
    if (lane == 0) out[b] = -acc;
}

extern "C" void kernel_launch(void* const* d_in, const int* in_sizes, int n_in,
                              void* d_out, int out_size, void* d_ws, size_t ws_size,
                              hipStream_t stream) {
    (void)d_ws; (void)ws_size; (void)in_sizes; (void)n_in; (void)out_size;
    const float* log_probs = (const float*)d_in[0];       // 255*64*5000
    const int* targets = (const int*)d_in[1];             // 50*64
    const int* target_lengths = (const int*)d_in[2];      // 64
    float* out = (float*)d_out;                           // 64

    // Zero-workspace path: never touch d_ws, so the harness's 1.3 GB
    // workspace poison fill cannot appear on our critical path.
    ctreec_fused_lin<<<dim3(BB), dim3(512), 0, stream>>>(
        log_probs, targets, target_lengths, out);
}

// Round 2
// 384.977 us; speedup vs baseline: 1.1816x; 1.1816x over previous
//
#include <hip/hip_runtime.h>
#include <math.h>

// CTreeC loss: DEPTH=7, V=255 states, B=64, T=50, vocab=5000.
// R5: split kernels (R3 structure — the 3200-block gather has the TLP the
// fused version lacked) + rebuilt scan:
//  * rank permutation: nodes sorted by source-count k into slots with
//    per-slot compile-time max sources {7,4,2,1} -> 14 fixed unrolled
//    ds_read_b32 (pad index 255 reads a guaranteed 0), replacing runtime-
//    trip-count loops that serialized at ~130cy/read.
//  * stale-sqrt normalization: telescoping is exact for ANY per-step scalar
//    S (acc += log S / state /= S cancels algebraically), so S_t =
//    sqrt(R_{t-2}) where R = sum_OUT(c), reduced by a 2-level LDS tree
//    pipelined across 2 iterations -> the 6-round shfl chain leaves the
//    critical path. Damping: char roots |z| = {0.56, 0.945} < 1 (stable;
//    plain stale-2 without sqrt has |z|=1.15 and diverges).
//  * ews stored rank-permuted -> cur loads & outv writes coalesced stride-64.
// Fills (2 x ~199us harness workspace poison) are unconditional; floor ~399us.
//
// Tree structure (in-order numbering), p = v+1:
//   START <=> p power of 2; END <=> p + (p&-p) == 256; OUT = non-END (247).
//   non-START x: s=ctz(p), j=x-2^s, k=ctz(p&(p-1)); sources {j-2^a: a<k}.
// Rank: k=ctz(p&(p-1)), m=p>>(k+1), a=ctz(p); rank = off[k] + m*k + a,
//   off[k] = sum_{kap>k} kap*2^(7-kap); START: 247+ctz(p); pad: 255.
//   Slot i holds ranks [64i,64i+64): k-ranges [4,7],[2,4],[1,2],[0,1].

#define TT 50
#define BB 64
#define VOCAB 5000
#define NS 255
#define NSP 256
#define WS_NEEDED ((size_t)BB * TT * NSP * 4)
#define LOG_EPS_F (-64.0f)
#define EPS_F 1.6038109389511818e-28f  // exp(-64)

__device__ __forceinline__ int rank_of(int v) {
    // v in [0, NS) -> rank in [0, 255)
    int p = v + 1;
    if ((p & (p - 1)) == 0) return 247 + (__ffs(p) - 1);
    int a = __ffs(p) - 1;
    int q = p & (p - 1);
    int k = __ffs(q) - 1;
    int m = p >> (k + 1);
    int off = 0;
#pragma unroll
    for (int kap = 7; kap >= 1; --kap)
        if (kap > k) off += kap << (7 - kap);
    return off + m * k + a;
}

// ---- Kernel A: ews[b][t][rank(v)] = exp(log_probs[v][b][targets[t][b]]) ----
__global__ __launch_bounds__(256) void gather_kernel(
    const float* __restrict__ log_probs,
    const int* __restrict__ targets,
    const int* __restrict__ target_lengths,
    float* __restrict__ ews)
{
    const int bt = blockIdx.x;          // b*TT + t
    const int b = bt / TT;
    const int t = bt % TT;
    if (t >= target_lengths[b]) return; // uniform branch, block exits
    const int v = threadIdx.x;
    const int tgt = targets[t * BB + b];
    float val = 0.0f;
    int r = 255;                        // pad slot: must be 0 (adds nothing)
    if (v < NS) {
        val = __expf(log_probs[(size_t)v * (BB * VOCAB) + (size_t)b * VOCAB + tgt]);
        r = rank_of(v);
    }
    ews[(size_t)bt * NSP + r] = val;    // permuted scatter within 1KB row
}

// ---- Kernel B: linear-domain serial scan, one wave per batch element ----
__global__ __launch_bounds__(64) void scan_kernel(
    const float* __restrict__ ews,
    const int* __restrict__ target_lengths,
    float* __restrict__ out)
{
    const int b = blockIdx.x;
    const int L = threadIdx.x;

    __shared__ __align__(16) float outv[NSP];   // c values, rank-indexed
    __shared__ __align__(16) float pb[2][64];   // reduce stage-0 partials
    __shared__ __align__(16) float gb[2][16];   // reduce stage-1 group sums
    __shared__ int node_of[NSP];

    const int len = target_lengths[b];
    const float* erow = ews + (size_t)b * TT * NSP;

    // ---- init: build rank -> node table (bijection, verified) ----
#pragma unroll
    for (int i = 0; i < 4; ++i) {
        int v = 4 * L + i;
        if (v < NS) node_of[rank_of(v)] = v;
    }
    if (L == 0) node_of[255] = NS;      // pad
    __builtin_amdgcn_wave_barrier();
    __syncthreads();

    // per-slot static tree data for assigned (rank-space) nodes
    int n_[4];
    n_[0] = node_of[L];       n_[1] = node_of[64 + L];
    n_[2] = node_of[128 + L]; n_[3] = node_of[192 + L];

    float pm[4], em[4], prev[4];
    int kk[4], jj[4];
#pragma unroll
    for (int i = 0; i < 4; ++i) {
        int n = n_[i];
        int p = n + 1;
        bool valid = (n < NS);
        bool pw2 = (p & (p - 1)) == 0;
        bool e_ = valid && ((p + (p & (-p))) == 256);
        em[i] = e_ ? 1.0f : 0.0f;
        pm[i] = (valid && !e_) ? 1.0f : 0.0f;
        prev[i] = (valid && pw2) ? 1.0f : 0.0f;
        if (valid && !pw2) {
            int s = __ffs(p) - 1;
            jj[i] = n - (1 << s);
            kk[i] = __ffs(p & (p - 1)) - 1;
        } else { kk[i] = 0; jj[i] = 0; }
    }
    // source addresses in RANK space, padded to per-slot max {7,4,2,1};
    // pad -> 255 (outv[255] is written 0 every step by the pad slot)
    int adr0[7], adr1[4], adr2[2], adr3_;
#pragma unroll
    for (int a = 0; a < 7; ++a) {
        int x = jj[0] - (1 << a);
        adr0[a] = (a < kk[0]) ? rank_of(x < 0 ? 0 : x) : 255;
    }
#pragma unroll
    for (int a = 0; a < 4; ++a) {
        int x = jj[1] - (1 << a);
        adr1[a] = (a < kk[1]) ? rank_of(x < 0 ? 0 : x) : 255;
    }
#pragma unroll
    for (int a = 0; a < 2; ++a) {
        int x = jj[2] - (1 << a);
        adr2[a] = (a < kk[2]) ? rank_of(x < 0 ? 0 : x) : 255;
    }
    {
        int x = jj[3] - 1;
        adr3_ = (0 < kk[3]) ? rank_of(x < 0 ? 0 : x) : 255;
    }

    float acc = 0.0f;
    float c[4];
    float rA[4], rB[4];                 // cur prefetch, depth 2
    {
        const float* rp0 = erow;
        rA[0] = rp0[L]; rA[1] = rp0[64 + L];
        rA[2] = rp0[128 + L]; rA[3] = rp0[192 + L];
        const float* rp1 = erow + ((len > 1) ? NSP : 0);
        rB[0] = rp1[L]; rB[1] = rp1[64 + L];
        rB[2] = rp1[128 + L]; rB[3] = rp1[192 + L];
    }

#define PREF(REG, row) do { if ((row) < len) { \
        const float* _rp = erow + (size_t)(row) * NSP; \
        REG[0] = _rp[L]; REG[1] = _rp[64 + L]; \
        REG[2] = _rp[128 + L]; REG[3] = _rp[192 + L]; } } while (0)

    // Per step u: c = prev*cur; stage c + local OUT-partial P_u; np-gather;
    // stage2 completes R_{u-2} (rinv = rsqrt, acc += 0.5*log); stage1 folds
    // P_{u-1} 64->16. S_u = sqrt(R_{u-2}) for u>=2 else 1 (telescopes exactly).
#define STEP(tt, PAR, CREG) do { \
    c[0] = prev[0] * CREG[0]; c[1] = prev[1] * CREG[1]; \
    c[2] = prev[2] * CREG[2]; c[3] = prev[3] * CREG[3]; \
    PREF(CREG, (tt) + 2); \
    if ((tt) == len - 1) goto final_step; \
    { \
        float P = (c[0] * pm[0] + c[1] * pm[1]) + (c[2] * pm[2] + c[3] * pm[3]); \
        outv[L] = c[0]; outv[64 + L] = c[1]; \
        outv[128 + L] = c[2]; outv[192 + L] = c[3]; \
        pb[PAR][L] = P; \
        __builtin_amdgcn_wave_barrier(); \
        float np0, np1, np2, np3; \
        { float r0 = outv[adr0[0]], r1 = outv[adr0[1]], r2 = outv[adr0[2]], \
                r3 = outv[adr0[3]], r4 = outv[adr0[4]], r5 = outv[adr0[5]], \
                r6 = outv[adr0[6]]; \
          np0 = ((r0 + r1) + (r2 + r3)) + ((r4 + r5) + r6); } \
        { float r0 = outv[adr1[0]], r1 = outv[adr1[1]], r2 = outv[adr1[2]], \
                r3 = outv[adr1[3]]; \
          np1 = (r0 + r1) + (r2 + r3); } \
        np2 = outv[adr2[0]] + outv[adr2[1]]; \
        np3 = outv[adr3_]; \
        float rinv = 1.0f; \
        if ((tt) >= 2) { \
            float4 g0 = *(const float4*)&gb[PAR][0]; \
            float4 g1 = *(const float4*)&gb[PAR][4]; \
            float4 g2 = *(const float4*)&gb[PAR][8]; \
            float4 g3 = *(const float4*)&gb[PAR][12]; \
            float R = ((((g0.x + g0.y) + (g0.z + g0.w)) + \
                        ((g1.x + g1.y) + (g1.z + g1.w))) + \
                       (((g2.x + g2.y) + (g2.z + g2.w)) + \
                        ((g3.x + g3.y) + (g3.z + g3.w)))); \
            rinv = rsqrtf(R); \
            acc += 0.5f * __logf(R); \
        } \
        if ((tt) >= 1) { \
            float4 q = *(const float4*)&pb[PAR ^ 1][4 * (L & 15)]; \
            gb[PAR ^ 1][L & 15] = (q.x + q.y) + (q.z + q.w); \
        } \
        prev[0] = np0 * rinv; prev[1] = np1 * rinv; \
        prev[2] = np2 * rinv; prev[3] = np3 * rinv; \
    } \
} while (0)

    for (int t = 0; ; t += 2) {
        STEP(t, 0, rA);
        STEP(t + 1, 1, rB);
    }

final_step:
    {
        // exact END-sum of current (scaled) c; scaling telescopes out exactly
        float E = (c[0] * em[0] + c[1] * em[1]) + (c[2] * em[2] + c[3] * em[3]);
        pb[0][L] = E;
        __builtin_amdgcn_wave_barrier();
        float tot = 0.0f;
#pragma unroll
        for (int g = 0; g < 16; ++g) {
            float4 q = *(const float4*)&pb[0][4 * g];   // uniform addr: broadcast
            tot += (q.x + q.y) + (q.z + q.w);
        }
        acc += __logf(tot);
        if (L == 0) out[b] = -acc;
    }
#undef STEP
#undef PREF
}

// ---- Fallback (ws too small): R4 fused zero-workspace kernel (verified) ----
__global__ __launch_bounds__(512) void ctreec_fused_lin(
    const float* __restrict__ log_probs,
    const int* __restrict__ targets,
    const int* __restrict__ target_lengths,
    float* __restrict__ out)
{
    const int b = blockIdx.x;
    const int tid = threadIdx.x;
    __shared__ float e_lds[TT * NSP];
    __shared__ float outv[NSP];
    __shared__ int tgts[TT];
    const int len = target_lengths[b];
    if (tid < TT) tgts[tid] = targets[tid * BB + b];
    __syncthreads();
    {
        const int v = tid & (NSP - 1);
        const int th = tid >> 8;
        if (v < NS) {
            const float* row = log_probs + (size_t)v * (BB * VOCAB) + (size_t)b * VOCAB;
            for (int t = th; t < len; t += 2)
                e_lds[t * NSP + v] = __expf(row[tgts[t]]);
        } else {
            for (int t = th; t < len; t += 2)
                e_lds[t * NSP + v] = 0.0f;
        }
    }
    __syncthreads();
    if (tid >= 64) return;
    const int lane = tid;
    const int vbase = lane * 4;
    bool isend[4], isout[4];
    int kk[4], jj[4];
    float prev[4];
#pragma unroll
    for (int i = 0; i < 4; ++i) {
        int v = vbase + i;
        int p = v + 1;
        bool valid = (v < NS);
        bool pw2 = (p & (p - 1)) == 0;
        bool e_ = valid && ((p + (p & (-p))) == 256);
        isend[i] = e_;
        isout[i] = valid && !e_;
        prev[i] = (valid && pw2) ? 1.0f : 0.0f;
        if (valid && !pw2) {
            int s = __ffs(p) - 1;
            kk[i] = __ffs(p & (p - 1)) - 1;
            jj[i] = v - (1 << s);
        } else { kk[i] = 0; jj[i] = 0; }
    }
    const float4* ev = (const float4*)e_lds;
    float acc = 0.0f;
    float4 eA = ev[lane];
    for (int t = 0; t < len; ++t) {
        float4 cur = eA;
        if (t + 1 < len) eA = ev[(t + 1) * 64 + lane];
        float cc[4];
        cc[0] = prev[0] * cur.x; cc[1] = prev[1] * cur.y;
        cc[2] = prev[2] * cur.z; cc[3] = prev[3] * cur.w;
        if (t == len - 1) {
            float s = 0.0f;
#pragma unroll
            for (int i = 0; i < 4; ++i) if (isend[i]) s += cc[i];
#pragma unroll
            for (int m = 32; m >= 1; m >>= 1) s += __shfl_xor(s, m);
            acc += __logf(s);
        } else {
            *(float4*)&outv[vbase] = make_float4(cc[0], cc[1], cc[2], cc[3]);
            float s = 0.0f;
#pragma unroll
            for (int i = 0; i < 4; ++i) if (isout[i]) s += cc[i];
#pragma unroll
            for (int m = 32; m >= 1; m >>= 1) s += __shfl_xor(s, m);
            acc += __logf(s);
            float rinv = 1.0f / s;
            __builtin_amdgcn_wave_barrier();
#pragma unroll
            for (int i = 0; i < 4; ++i) {
                float np_ = 0.0f;
                int bj = jj[i];
                int n = kk[i];
                for (int a = 0; a < n; ++a) np_ += outv[bj - (1 << a)];
                prev[i] = np_ * rinv;
            }
            __builtin_amdgcn_wave_barrier();
        }
    }
    if (lane == 0) out[b] = -acc;
}

extern "C" void kernel_launch(void* const* d_in, const int* in_sizes, int n_in,
                              void* d_out, int out_size, void* d_ws, size_t ws_size,
                              hipStream_t stream) {
    (void)in_sizes; (void)n_in; (void)out_size;
    const float* log_probs = (const float*)d_in[0];       // 255*64*5000
    const int* targets = (const int*)d_in[1];             // 50*64
    const int* target_lengths = (const int*)d_in[2];      // 64
    float* out = (float*)d_out;                           // 64

    if (ws_size >= WS_NEEDED) {
        float* ews = (float*)d_ws;
        gather_kernel<<<dim3(BB * TT), dim3(256), 0, stream>>>(
            log_probs, targets, target_lengths, ews);
        scan_kernel<<<dim3(BB), dim3(64), 0, stream>>>(
            ews, target_lengths, out);
    } else {
        ctreec_fused_lin<<<dim3(BB), dim3(512), 0, stream>>>(
            log_probs, targets, target_lengths, out);
    }
}